// Round 18
// baseline (4316.776 us; speedup 1.0000x reference)
//
#include <hip/hip_runtime.h>

#define BB   256
#define TT   2048
#define HH   128
#define G4   512
#define INW  4
#define OUTW 4
#define TC   32        // chunk; 2048/32 = 64 uniform chunks
#define NCH  64
#define NT   256       // 4 waves -> 256-VGPR budget (131072/(256*2))

typedef _Float16 f16x8 __attribute__((ext_vector_type(8)));
typedef float    f32x4 __attribute__((ext_vector_type(4)));

#define MFMA(A,B,C) __builtin_amdgcn_mfma_f32_16x16x32_f16((A),(B),(C),0,0,0)

__device__ __forceinline__ float sigm(float x)  { return __fdividef(1.f, 1.f + __expf(-x)); }
__device__ __forceinline__ float tanh_(float x) { return __fdividef(2.f, 1.f + __expf(-2.f*x)) - 1.f; }

// R18: layer pipeline across block pairs (even = layer0 producer, odd = layer1
// consumer), handoff via d_ws slots + agent-scope atomics/fences (cross-XCD).
// Replay-safe sync: both blocks fetch_add the same pair counter; g = val>>1 is
// equal in both and unique per launch (base even: fresh 0, poison 0xAAAAAAAA).
// Flags compare EXACT value TAG(c) = (g<<7)|(c+1) -> stale/poison never match.
// NT=256 -> 256-VGPR budget -> 8 tiles/wave (128 frag VGPRs) legal.
// Layout (verified R11-R17, extended to 8 tiles): tile T = 8w+j;
//   wrow_j(r) = ((r&3)<<7)|(T<<2)|(r>>2) = wr0 + 4j; B-frag h broadcast;
//   lane (r,kq) acc_j[e] = gate e of unit (8w+j)*4+kq; select j = r&7;
//   unit u = (w<<5)|((r&7)<<2)|kq; owner lanes r<8; xg col = 4u+g.

#define LDF(dst, wrj, kk) do {                                                 \
    const float* p_ = Mp_ + (size_t)(wrj) * HH + (kk)*32 + (kq << 3);          \
    const float4 lo_ = *(const float4*)p_;                                     \
    const float4 hi_ = *(const float4*)(p_ + 4);                               \
    dst = (f16x8){(_Float16)lo_.x,(_Float16)lo_.y,(_Float16)lo_.z,             \
                  (_Float16)lo_.w,(_Float16)hi_.x,(_Float16)hi_.y,             \
                  (_Float16)hi_.z,(_Float16)hi_.w}; } while (0)

#define LOADW8(M) do { const float* Mp_ = (M);                                 \
    LDF(w00, wr0,      0); LDF(w01, wr0,      1); LDF(w02, wr0,      2); LDF(w03, wr0,      3); \
    LDF(w10, wr0 + 4,  0); LDF(w11, wr0 + 4,  1); LDF(w12, wr0 + 4,  2); LDF(w13, wr0 + 4,  3); \
    LDF(w20, wr0 + 8,  0); LDF(w21, wr0 + 8,  1); LDF(w22, wr0 + 8,  2); LDF(w23, wr0 + 8,  3); \
    LDF(w30, wr0 + 12, 0); LDF(w31, wr0 + 12, 1); LDF(w32, wr0 + 12, 2); LDF(w33, wr0 + 12, 3); \
    LDF(w40, wr0 + 16, 0); LDF(w41, wr0 + 16, 1); LDF(w42, wr0 + 16, 2); LDF(w43, wr0 + 16, 3); \
    LDF(w50, wr0 + 20, 0); LDF(w51, wr0 + 20, 1); LDF(w52, wr0 + 20, 2); LDF(w53, wr0 + 20, 3); \
    LDF(w60, wr0 + 24, 0); LDF(w61, wr0 + 24, 1); LDF(w62, wr0 + 24, 2); LDF(w63, wr0 + 24, 3); \
    LDF(w70, wr0 + 28, 0); LDF(w71, wr0 + 28, 1); LDF(w72, wr0 + 28, 2); LDF(w73, wr0 + 28, 3); \
} while (0)

#define RS1(kk, OFS) do {                                                      \
    const f16x8 hv_ = *(const f16x8*)(HB_ + (OFS) + (kq << 3));                \
    a0 = MFMA(w0##kk, hv_, a0); a1 = MFMA(w1##kk, hv_, a1);                    \
    a2 = MFMA(w2##kk, hv_, a2); a3 = MFMA(w3##kk, hv_, a3);                    \
    a4 = MFMA(w4##kk, hv_, a4); a5 = MFMA(w5##kk, hv_, a5);                    \
    a6 = MFMA(w6##kk, hv_, a6); a7 = MFMA(w7##kk, hv_, a7); } while (0)

#define RSTEP8(HBP) do { const _Float16* HB_ = (HBP);                          \
    RS1(0, 0); RS1(1, 32); RS1(2, 64); RS1(3, 96); } while (0)

#define BS1(kk) do {                                                           \
    const f16x8 tv_ = *(const f16x8*)(ar_ + (kk)*32 + (kq << 3));              \
    a0 = MFMA(tv_, w0##kk, a0); a1 = MFMA(tv_, w1##kk, a1);                    \
    a2 = MFMA(tv_, w2##kk, a2); a3 = MFMA(tv_, w3##kk, a3);                    \
    a4 = MFMA(tv_, w4##kk, a4); a5 = MFMA(tv_, w5##kk, a5);                    \
    a6 = MFMA(tv_, w6##kk, a6); a7 = MFMA(tv_, w7##kk, a7); } while (0)

// select my tile j = r&7 from 8 acc vectors, add XG, lane-local LSTM update
#define UPDSEL8(CJ, HN, XG) do {                                               \
    f32x4 av_;                                                                 \
    _Pragma("unroll")                                                          \
    for (int e_ = 0; e_ < 4; ++e_) {                                           \
        const float s01_ = j1b ? a1[e_] : a0[e_];                              \
        const float s23_ = j1b ? a3[e_] : a2[e_];                              \
        const float s45_ = j1b ? a5[e_] : a4[e_];                              \
        const float s67_ = j1b ? a7[e_] : a6[e_];                              \
        const float sA_ = j2b ? s23_ : s01_;                                   \
        const float sB_ = j2b ? s67_ : s45_;                                   \
        av_[e_] = (j4b ? sB_ : sA_) + (XG)[e_];                                \
    }                                                                          \
    const float i_ = sigm(av_[0]);                                             \
    const float f_ = sigm(av_[1]);                                             \
    const float g_ = tanh_(av_[2]);                                            \
    const float o_ = sigm(av_[3]);                                             \
    CJ = f_ * CJ + i_ * g_;                                                    \
    HN = o_ * tanh_(CJ); } while (0)

#define PROJ(OFS, VT) do {                                                     \
    float p2_ = (float)h2h[(OFS) + pl] * wlA                                   \
              + (float)h2h[(OFS) + 64 + pl] * wlB;                             \
    p2_ += __shfl_xor(p2_, 32);                                                \
    p2_ += __shfl_xor(p2_, 16);                                                \
    p2_ += __shfl_xor(p2_, 8);                                                 \
    p2_ += __shfl_xor(p2_, 4);                                                 \
    p2_ += __shfl_xor(p2_, 2);                                                 \
    p2_ += __shfl_xor(p2_, 1);                                                 \
    if (pl == 0) vbuf[(VT) * OUTW + po] = p2_ + bl; } while (0)

#define TAG(C) (((g) << 7) | (unsigned)((C) + 1))

extern "C" __global__ void
__attribute__((amdgpu_flat_work_group_size(NT, NT)))
lstm2_pipe(const float* __restrict__ x,
           const float* __restrict__ Wih0, const float* __restrict__ Whh0,
           const float* __restrict__ bih0, const float* __restrict__ bhh0,
           const float* __restrict__ Wih1, const float* __restrict__ Whh1,
           const float* __restrict__ bih1, const float* __restrict__ bhh1,
           const float* __restrict__ Wlin, const float* __restrict__ blin,
           float* __restrict__ out,
           unsigned* __restrict__ genPair, unsigned* __restrict__ flagsA,
           unsigned* __restrict__ doneA, _Float16* __restrict__ slots, int S)
{
    __shared__ __align__(16) _Float16 ring[(TC + 1) * HH];  // producer h1 ring
    __shared__ __align__(16) float    xgbuf[TC * G4];       // consumer xg1 (fp32)
    __shared__ __align__(16) _Float16 h2h[2 * HH];          // consumer h2 dbuf
    __shared__ __align__(16) float    vbuf[TC * OUTW];      // consumer v staging
    __shared__ unsigned gshare;

    const int i    = threadIdx.x;
    const int w    = i >> 6;            // wave 0..3 -> tiles 8w..8w+7
    const int lane = i & 63;
    const int r    = lane & 15;
    const int kq   = lane >> 4;
    const int bp   = blockIdx.x >> 1;   // pair = batch element
    const int role = blockIdx.x & 1;

    const int wr0 = ((r & 3) << 7) | (w << 5) | (r >> 2);
    const bool j1b = (r & 1), j2b = (r & 2), j4b = (r & 4);
    const int  u   = (w << 5) | ((r & 7) << 2) | kq;   // my unit
    const bool own = (r < 8);

    // pair-generation: both blocks fetch_add the same counter; >>1 equalizes.
    if (i == 0)
        gshare = __hip_atomic_fetch_add(&genPair[bp], 1u, __ATOMIC_RELAXED,
                                        __HIP_MEMORY_SCOPE_AGENT) >> 1;
    __syncthreads();
    const unsigned g = gshare;

    unsigned* myflag = flagsA + bp * NCH;
    unsigned* mydone = doneA  + bp * NCH;
    _Float16* myslot0 = slots + (size_t)bp * S * (TC * HH);

    f16x8 w00,w01,w02,w03, w10,w11,w12,w13, w20,w21,w22,w23, w30,w31,w32,w33,
          w40,w41,w42,w43, w50,w51,w52,w53, w60,w61,w62,w63, w70,w71,w72,w73;

    if (role == 0) {
        // ===================== PRODUCER: layer 0 =====================
        const float* xb = x + (size_t)bp * TT * INW;
        // Wih0 rows for my unit's 4 gates (thread-constant)
        const float4 wxa = *(const float4*)(Wih0 + (size_t)u * INW);
        const float4 wxb = *(const float4*)(Wih0 + (size_t)(128 + u) * INW);
        const float4 wxc = *(const float4*)(Wih0 + (size_t)(256 + u) * INW);
        const float4 wxd = *(const float4*)(Wih0 + (size_t)(384 + u) * INW);
        const float b0a = bih0[u]       + bhh0[u];
        const float b0b = bih0[128 + u] + bhh0[128 + u];
        const float b0c = bih0[256 + u] + bhh0[256 + u];
        const float b0d = bih0[384 + u] + bhh0[384 + u];
        LOADW8(Whh0);                      // resident for the whole kernel
        if (i < HH) ring[i] = (_Float16)0.f;
        float c1 = 0.f;
        __syncthreads();

        for (int c = 0; c < NCH; ++c) {
            const int t0 = c * TC;
            if (c >= S) {                  // backpressure: slot c%S free?
                if (i == 0) {
                    const unsigned exp_ = TAG(c - S);
                    while (__hip_atomic_load(&mydone[c - S], __ATOMIC_RELAXED,
                                             __HIP_MEMORY_SCOPE_AGENT) != exp_)
                        __builtin_amdgcn_s_sleep(8);
                }
                __syncthreads();
                __builtin_amdgcn_fence(__ATOMIC_ACQUIRE, "agent");
            }
            if (c > 0) {
                if (i < HH) ring[i] = ring[TC * HH + i];   // carry
                __syncthreads();
            }
            for (int t = 0; t < TC; ++t) {
                f32x4 a0={0,0,0,0},a1={0,0,0,0},a2={0,0,0,0},a3={0,0,0,0},
                      a4={0,0,0,0},a5={0,0,0,0},a6={0,0,0,0},a7={0,0,0,0};
                RSTEP8(ring + t * HH);
                const float4 xv = *(const float4*)(xb + (size_t)(t0 + t) * INW);
                f32x4 xg;
                xg[0] = b0a + wxa.x*xv.x + wxa.y*xv.y + wxa.z*xv.z + wxa.w*xv.w;
                xg[1] = b0b + wxb.x*xv.x + wxb.y*xv.y + wxb.z*xv.z + wxb.w*xv.w;
                xg[2] = b0c + wxc.x*xv.x + wxc.y*xv.y + wxc.z*xv.z + wxc.w*xv.w;
                xg[3] = b0d + wxd.x*xv.x + wxd.y*xv.y + wxd.z*xv.z + wxd.w*xv.w;
                float hn;
                UPDSEL8(c1, hn, xg);
                if (own) ring[(t + 1) * HH + u] = (_Float16)hn;
                __syncthreads();
            }
            // publish chunk: LDS rows 1..TC -> slot, fence, flag
            {
                unsigned* dst = (unsigned*)(myslot0 + (size_t)(c % S) * (TC * HH));
                const unsigned* src = (const unsigned*)(ring + HH);
                for (int jj = i; jj < TC * HH / 2; jj += NT) dst[jj] = src[jj];
            }
            __builtin_amdgcn_fence(__ATOMIC_RELEASE, "agent");
            __syncthreads();
            if (i == 0)
                __hip_atomic_store(&myflag[c], TAG(c), __ATOMIC_RELEASE,
                                   __HIP_MEMORY_SCOPE_AGENT);
        }
    } else {
        // ===================== CONSUMER: layer 1 =====================
        float* vout = out + (size_t)bp * TT * OUTW;
        float* zout = out + (size_t)BB * TT * OUTW + (size_t)bp * HH;
        // bias1 for my 8 tiles' row r (thread-constant)
        const float bb0 = bih1[wr0]      + bhh1[wr0];
        const float bb1 = bih1[wr0 + 4]  + bhh1[wr0 + 4];
        const float bb2 = bih1[wr0 + 8]  + bhh1[wr0 + 8];
        const float bb3 = bih1[wr0 + 12] + bhh1[wr0 + 12];
        const float bb4 = bih1[wr0 + 16] + bhh1[wr0 + 16];
        const float bb5 = bih1[wr0 + 20] + bhh1[wr0 + 20];
        const float bb6 = bih1[wr0 + 24] + bhh1[wr0 + 24];
        const float bb7 = bih1[wr0 + 28] + bhh1[wr0 + 28];
        const int   po = i >> 6;           // projection: wave = output
        const int   pl = i & 63;
        const float wlA = Wlin[po * HH + pl];
        const float wlB = Wlin[po * HH + 64 + pl];
        const float bl  = blin[po];
        if (i < HH) h2h[i] = (_Float16)0.f;
        float c2 = 0.f;
        __syncthreads();

        for (int c = 0; c < NCH; ++c) {
            const int t0 = c * TC;
            LOADW8(Wih1);                   // read-only: stale-safe, pre-spin
            if (i == 0) {
                const unsigned exp_ = TAG(c);
                while (__hip_atomic_load(&myflag[c], __ATOMIC_RELAXED,
                                         __HIP_MEMORY_SCOPE_AGENT) != exp_)
                    __builtin_amdgcn_s_sleep(8);
            }
            __syncthreads();
            __builtin_amdgcn_fence(__ATOMIC_ACQUIRE, "agent");  // inv L2: fresh h1
            const _Float16* sc = myslot0 + (size_t)(c % S) * (TC * HH);

            // phase B: xg1 = Wih1 @ h1 + b1 (A-frags straight from slot)
            for (int tb = 0; tb < TC / 16; ++tb) {
                f32x4 a0={0,0,0,0},a1={0,0,0,0},a2={0,0,0,0},a3={0,0,0,0},
                      a4={0,0,0,0},a5={0,0,0,0},a6={0,0,0,0},a7={0,0,0,0};
                const _Float16* ar_ = sc + (size_t)(tb * 16 + r) * HH;
                BS1(0); BS1(1); BS1(2); BS1(3);
                #pragma unroll
                for (int e = 0; e < 4; ++e) {
                    const int tl = tb * 16 + (kq << 2) + e;   // C row = time
                    float* bq = xgbuf + tl * G4 + (w << 7) + r;
                    bq[0]   = a0[e] + bb0;  bq[16]  = a1[e] + bb1;
                    bq[32]  = a2[e] + bb2;  bq[48]  = a3[e] + bb3;
                    bq[64]  = a4[e] + bb4;  bq[80]  = a5[e] + bb5;
                    bq[96]  = a6[e] + bb6;  bq[112] = a7[e] + bb7;
                }
            }
            __syncthreads();
            if (i == 0)                     // slot consumed
                __hip_atomic_store(&mydone[c], TAG(c), __ATOMIC_RELEASE,
                                   __HIP_MEMORY_SCOPE_AGENT);
            LOADW8(Whh1);

            // phase C: layer-1 recurrence + pipelined projection
            for (int t = 0; t < TC; ++t) {
                const int rb = (t & 1) * HH, wb2 = rb ^ HH;
                f32x4 a0={0,0,0,0},a1={0,0,0,0},a2={0,0,0,0},a3={0,0,0,0},
                      a4={0,0,0,0},a5={0,0,0,0},a6={0,0,0,0},a7={0,0,0,0};
                RSTEP8(h2h + rb);
                if (t > 0) PROJ(rb, t - 1);          // under the MFMA shadow
                const f32x4 xg = *(const f32x4*)(xgbuf + t * G4 + (u << 2));
                float hn;
                UPDSEL8(c2, hn, xg);
                if (own) {
                    h2h[wb2 + u] = (_Float16)hn;
                    if (t0 + t == TT - 1) zout[u] = hn;
                }
                __syncthreads();
            }
            PROJ(0, TC - 1);                // final h2 sits in buffer 0
            __syncthreads();
            for (int jj = i; jj < TC * OUTW; jj += NT)
                vout[(size_t)t0 * OUTW + jj] = vbuf[jj];
        }
    }
}

extern "C" void kernel_launch(void* const* d_in, const int* in_sizes, int n_in,
                              void* d_out, int out_size, void* d_ws, size_t ws_size,
                              hipStream_t stream) {
    const float* x    = (const float*)d_in[0];
    const float* Wih0 = (const float*)d_in[1];
    const float* Whh0 = (const float*)d_in[2];
    const float* bih0 = (const float*)d_in[3];
    const float* bhh0 = (const float*)d_in[4];
    const float* Wih1 = (const float*)d_in[5];
    const float* Whh1 = (const float*)d_in[6];
    const float* bih1 = (const float*)d_in[7];
    const float* bhh1 = (const float*)d_in[8];
    const float* Wlin = (const float*)d_in[9];
    const float* blin = (const float*)d_in[10];
    float* out = (float*)d_out;

    // d_ws layout: genPair[256] | flags[256*NCH] | done[256*NCH] | slots
    unsigned* wsu     = (unsigned*)d_ws;
    unsigned* genPair = wsu;
    unsigned* flagsA  = wsu + BB;
    unsigned* doneA   = flagsA + BB * NCH;
    const size_t hdr_u = (size_t)BB + 2u * BB * NCH;       // uints (132,096 B)
    _Float16* slots = (_Float16*)(wsu + hdr_u);
    const size_t slot_halfs = (size_t)TC * HH;             // 4096 halfs = 8KB
    long long avail = ((long long)ws_size - (long long)(hdr_u * 4)) / 2;
    int S = (avail > 0) ? (int)(avail / (long long)(BB * slot_halfs)) : 1;
    if (S < 1) S = 1;
    if (S > NCH) S = NCH;

    lstm2_pipe<<<dim3(2 * BB), dim3(NT), 0, stream>>>(
        x, Wih0, Whh0, bih0, bhh0, Wih1, Whh1, bih1, bhh1, Wlin, blin, out,
        genPair, flagsA, doneA, slots, S);
}

// Round 19
// 4014.590 us; speedup vs baseline: 1.0753x; 1.0753x over previous
//
#include <hip/hip_runtime.h>

#define BB   256
#define TT   2048
#define HH   128
#define HP   136   // padded h1-row stride (f16): breaks phase-B bank conflicts
#define G4   512
#define INW  4
#define OUTW 4
#define TC   56    // time-chunk (2048 = 36*56 + 32, both even)
#define NT   256   // 4 waves, 8 tiles/wave; 256-VGPR budget (R18: 204 no-spill)

typedef _Float16 f16x8 __attribute__((ext_vector_type(8)));
typedef float    f32x4 __attribute__((ext_vector_type(4)));

#define MFMA(A,B,C) __builtin_amdgcn_mfma_f32_16x16x32_f16((A),(B),(C),0,0,0)

__device__ __forceinline__ float sigm(float x)  { return __fdividef(1.f, 1.f + __expf(-x)); }
__device__ __forceinline__ float tanh_(float x) { return __fdividef(2.f, 1.f + __expf(-2.f*x)) - 1.f; }

// R18 post-mortem: producer/consumer pipeline regressed (4317us, occupancy 11%:
// consumer chunk = B+C > half, CU contention, cross-XCD handoff). Reverted.
// R19 tests the last single-block axis: 4 waves x 32 MFMA/step instead of
// 8 x 16 — same per-SIMD MFMA issue, HALF the barrier-synced waves (skew),
// 1 wave/SIMD. xg0 folded into per-step registers (R18-producer style),
// deleting the xg0 bulk phase. Tile T = 8w+j, j selected by r&7;
// wrow_j(r) = ((r&3)<<7)|(w<<5)|(j<<2)|(r>>2); unit u = (w<<5)|((r&7)<<2)|kq;
// phase-B write col (w<<7)+16j+4kq+e == recurrence read col 4u+e (verified).

#define LDF(dst, wrj, kk) do {                                                 \
    const float* p_ = Mp_ + (size_t)(wrj) * HH + (kk)*32 + (kq << 3);          \
    const float4 lo_ = *(const float4*)p_;                                     \
    const float4 hi_ = *(const float4*)(p_ + 4);                               \
    dst = (f16x8){(_Float16)lo_.x,(_Float16)lo_.y,(_Float16)lo_.z,             \
                  (_Float16)lo_.w,(_Float16)hi_.x,(_Float16)hi_.y,             \
                  (_Float16)hi_.z,(_Float16)hi_.w}; } while (0)

#define LOADW8(M) do { const float* Mp_ = (M);                                 \
    LDF(w00, wr0,      0); LDF(w01, wr0,      1); LDF(w02, wr0,      2); LDF(w03, wr0,      3); \
    LDF(w10, wr0 + 4,  0); LDF(w11, wr0 + 4,  1); LDF(w12, wr0 + 4,  2); LDF(w13, wr0 + 4,  3); \
    LDF(w20, wr0 + 8,  0); LDF(w21, wr0 + 8,  1); LDF(w22, wr0 + 8,  2); LDF(w23, wr0 + 8,  3); \
    LDF(w30, wr0 + 12, 0); LDF(w31, wr0 + 12, 1); LDF(w32, wr0 + 12, 2); LDF(w33, wr0 + 12, 3); \
    LDF(w40, wr0 + 16, 0); LDF(w41, wr0 + 16, 1); LDF(w42, wr0 + 16, 2); LDF(w43, wr0 + 16, 3); \
    LDF(w50, wr0 + 20, 0); LDF(w51, wr0 + 20, 1); LDF(w52, wr0 + 20, 2); LDF(w53, wr0 + 20, 3); \
    LDF(w60, wr0 + 24, 0); LDF(w61, wr0 + 24, 1); LDF(w62, wr0 + 24, 2); LDF(w63, wr0 + 24, 3); \
    LDF(w70, wr0 + 28, 0); LDF(w71, wr0 + 28, 1); LDF(w72, wr0 + 28, 2); LDF(w73, wr0 + 28, 3); \
} while (0)

#define RS1(kk, OFS) do {                                                      \
    const f16x8 hv_ = *(const f16x8*)(HB_ + (OFS) + (kq << 3));                \
    a0 = MFMA(w0##kk, hv_, a0); a1 = MFMA(w1##kk, hv_, a1);                    \
    a2 = MFMA(w2##kk, hv_, a2); a3 = MFMA(w3##kk, hv_, a3);                    \
    a4 = MFMA(w4##kk, hv_, a4); a5 = MFMA(w5##kk, hv_, a5);                    \
    a6 = MFMA(w6##kk, hv_, a6); a7 = MFMA(w7##kk, hv_, a7); } while (0)

#define RSTEP8(HBP) do { const _Float16* HB_ = (HBP);                          \
    RS1(0, 0); RS1(1, 32); RS1(2, 64); RS1(3, 96); } while (0)

#define BS1(kk) do {                                                           \
    const f16x8 tv_ = *(const f16x8*)(ar_ + (kk)*32 + (kq << 3));              \
    a0 = MFMA(tv_, w0##kk, a0); a1 = MFMA(tv_, w1##kk, a1);                    \
    a2 = MFMA(tv_, w2##kk, a2); a3 = MFMA(tv_, w3##kk, a3);                    \
    a4 = MFMA(tv_, w4##kk, a4); a5 = MFMA(tv_, w5##kk, a5);                    \
    a6 = MFMA(tv_, w6##kk, a6); a7 = MFMA(tv_, w7##kk, a7); } while (0)

// select my tile j = r&7 from the 8 acc vectors, add XG, lane-local update
#define UPDSEL8(CJ, HN, XG) do {                                               \
    f32x4 av_;                                                                 \
    _Pragma("unroll")                                                          \
    for (int e_ = 0; e_ < 4; ++e_) {                                           \
        const float s01_ = j1b ? a1[e_] : a0[e_];                              \
        const float s23_ = j1b ? a3[e_] : a2[e_];                              \
        const float s45_ = j1b ? a5[e_] : a4[e_];                              \
        const float s67_ = j1b ? a7[e_] : a6[e_];                              \
        const float sA_ = j2b ? s23_ : s01_;                                   \
        const float sB_ = j2b ? s67_ : s45_;                                   \
        av_[e_] = (j4b ? sB_ : sA_) + (XG)[e_];                                \
    }                                                                          \
    const float i_ = sigm(av_[0]);                                             \
    const float f_ = sigm(av_[1]);                                             \
    const float g_ = tanh_(av_[2]);                                            \
    const float o_ = sigm(av_[3]);                                             \
    CJ = f_ * CJ + i_ * g_;                                                    \
    HN = o_ * tanh_(CJ); } while (0)

#define PROJ(OFS, VT) do {                                                     \
    float p2_ = (float)h2h[(OFS) + pl] * wlA                                   \
              + (float)h2h[(OFS) + 64 + pl] * wlB;                             \
    p2_ += __shfl_xor(p2_, 32);                                                \
    p2_ += __shfl_xor(p2_, 16);                                                \
    p2_ += __shfl_xor(p2_, 8);                                                 \
    p2_ += __shfl_xor(p2_, 4);                                                 \
    p2_ += __shfl_xor(p2_, 2);                                                 \
    p2_ += __shfl_xor(p2_, 1);                                                 \
    if (pl == 0) vbuf[(VT) * OUTW + po] = p2_ + bl; } while (0)

extern "C" __global__ void
__attribute__((amdgpu_flat_work_group_size(NT, NT)))
lstm2_fused(const float* __restrict__ x,
            const float* __restrict__ Wih0, const float* __restrict__ Whh0,
            const float* __restrict__ bih0, const float* __restrict__ bhh0,
            const float* __restrict__ Wih1, const float* __restrict__ Whh1,
            const float* __restrict__ bih1, const float* __restrict__ bhh1,
            const float* __restrict__ Wlin, const float* __restrict__ blin,
            float* __restrict__ out)
{
    // static LDS: 17,680 + 114,688 + 512 + 896 = 133,776 B
    __shared__ __align__(16) _Float16 h1h[(TC + 9) * HP]; // h1 ring (padded)
    __shared__ __align__(16) float    buf[TC * G4];       // xg1 only
    __shared__ __align__(16) _Float16 h2h[2 * HH];        // h2 dbuf, parity t&1
    __shared__ __align__(16) float    vbuf[TC * OUTW];    // v staging

    const int i    = threadIdx.x;
    const int w    = i >> 6;            // wave 0..3 -> tiles 8w..8w+7
    const int lane = i & 63;
    const int r    = lane & 15;
    const int kq   = lane >> 4;
    const int b    = blockIdx.x;

    const int wr0 = ((r & 3) << 7) | (w << 5) | (r >> 2);
    const bool j1b = (r & 1), j2b = (r & 2), j4b = (r & 4);
    const int  u   = (w << 5) | ((r & 7) << 2) | kq;   // my unit
    const bool own = (r < 8);

    // ---- kernel-lifetime register constants
    // layer-0 x-projection: Wih0 rows of my unit's 4 gates
    const float4 wxa = *(const float4*)(Wih0 + (size_t)u * INW);
    const float4 wxb = *(const float4*)(Wih0 + (size_t)(128 + u) * INW);
    const float4 wxc = *(const float4*)(Wih0 + (size_t)(256 + u) * INW);
    const float4 wxd = *(const float4*)(Wih0 + (size_t)(384 + u) * INW);
    const float b0a = bih0[u]       + bhh0[u];
    const float b0b = bih0[128 + u] + bhh0[128 + u];
    const float b0c = bih0[256 + u] + bhh0[256 + u];
    const float b0d = bih0[384 + u] + bhh0[384 + u];
    // layer-1 bias (by W-row of my 8 tiles at A-row r)
    const float bb0 = bih1[wr0]      + bhh1[wr0];
    const float bb1 = bih1[wr0 + 4]  + bhh1[wr0 + 4];
    const float bb2 = bih1[wr0 + 8]  + bhh1[wr0 + 8];
    const float bb3 = bih1[wr0 + 12] + bhh1[wr0 + 12];
    const float bb4 = bih1[wr0 + 16] + bhh1[wr0 + 16];
    const float bb5 = bih1[wr0 + 20] + bhh1[wr0 + 20];
    const float bb6 = bih1[wr0 + 24] + bhh1[wr0 + 24];
    const float bb7 = bih1[wr0 + 28] + bhh1[wr0 + 28];
    // projection constants (wave = output o, lane = part)
    const int   po = i >> 6;
    const int   pl = i & 63;
    const float wlA = Wlin[po * HH + pl];
    const float wlB = Wlin[po * HH + 64 + pl];
    const float bl  = blin[po];

    if (i < HH) { h1h[i] = (_Float16)0.f; h2h[i] = (_Float16)0.f; }

    float c1 = 0.f, c2 = 0.f;
    f16x8 w00,w01,w02,w03, w10,w11,w12,w13, w20,w21,w22,w23, w30,w31,w32,w33,
          w40,w41,w42,w43, w50,w51,w52,w53, w60,w61,w62,w63, w70,w71,w72,w73;

    const float* xb   = x   + (size_t)b * TT * INW;
    float*       vout = out + (size_t)b * TT * OUTW;
    float*       zout = out + (size_t)BB * TT * OUTW + (size_t)b * HH;

    for (int t0 = 0; t0 < TT; t0 += TC) {
        const int tc = (TT - t0 < TC) ? (TT - t0) : TC;

        if (t0 > 0 && i < HH) h1h[i] = h1h[TC * HP + i];   // carry h1 ring
        LOADW8(Whh0);
        __syncthreads();

        // ========= Phase A: layer-0 recurrence (xg0 inline, regs) ======
        for (int t = 0; t < tc; ++t) {
            f32x4 a0={0,0,0,0},a1={0,0,0,0},a2={0,0,0,0},a3={0,0,0,0},
                  a4={0,0,0,0},a5={0,0,0,0},a6={0,0,0,0},a7={0,0,0,0};
            RSTEP8(h1h + t * HP);
            const float4 xv = *(const float4*)(xb + (size_t)(t0 + t) * INW);
            f32x4 xg;
            xg[0] = b0a + wxa.x*xv.x + wxa.y*xv.y + wxa.z*xv.z + wxa.w*xv.w;
            xg[1] = b0b + wxb.x*xv.x + wxb.y*xv.y + wxb.z*xv.z + wxb.w*xv.w;
            xg[2] = b0c + wxc.x*xv.x + wxc.y*xv.y + wxc.z*xv.z + wxc.w*xv.w;
            xg[3] = b0d + wxd.x*xv.x + wxd.y*xv.y + wxd.z*xv.z + wxd.w*xv.w;
            float hn;
            UPDSEL8(c1, hn, xg);
            if (own) h1h[(t + 1) * HP + u] = (_Float16)hn;
            __syncthreads();
        }

        // ===== Phase B: xg1 = Wih1 @ h1 + b1 (bulk, A = h1 time-rows) ==
        LOADW8(Wih1);
        const int ntb = (tc + 15) >> 4;
        for (int tb = 0; tb < ntb; ++tb) {
            f32x4 a0={0,0,0,0},a1={0,0,0,0},a2={0,0,0,0},a3={0,0,0,0},
                  a4={0,0,0,0},a5={0,0,0,0},a6={0,0,0,0},a7={0,0,0,0};
            const _Float16* ar_ = h1h + (size_t)(tb * 16 + r + 1) * HP;
            BS1(0); BS1(1); BS1(2); BS1(3);
            #pragma unroll
            for (int e = 0; e < 4; ++e) {
                const int tl = tb * 16 + (kq << 2) + e;    // C row = time
                if (tl < tc) {
                    float* bq = buf + tl * G4 + (w << 7) + r;
                    bq[0]   = a0[e] + bb0;  bq[16]  = a1[e] + bb1;
                    bq[32]  = a2[e] + bb2;  bq[48]  = a3[e] + bb3;
                    bq[64]  = a4[e] + bb4;  bq[80]  = a5[e] + bb5;
                    bq[96]  = a6[e] + bb6;  bq[112] = a7[e] + bb7;
                }
            }
        }
        __syncthreads();

        // ====== Phase C: layer-1 recurrence + pipelined projection =====
        LOADW8(Whh1);
        for (int t = 0; t < tc; ++t) {
            const int rb = (t & 1) * HH, wb2 = rb ^ HH;
            f32x4 a0={0,0,0,0},a1={0,0,0,0},a2={0,0,0,0},a3={0,0,0,0},
                  a4={0,0,0,0},a5={0,0,0,0},a6={0,0,0,0},a7={0,0,0,0};
            RSTEP8(h2h + rb);
            if (t > 0) PROJ(rb, t - 1);           // under the MFMA shadow
            const f32x4 xg = *(const f32x4*)(buf + t * G4 + (u << 2));
            float hn;
            UPDSEL8(c2, hn, xg);
            if (own) {
                h2h[wb2 + u] = (_Float16)hn;
                if (t0 + t == TT - 1) zout[u] = hn;
            }
            __syncthreads();
        }
        PROJ((tc & 1) * HH, tc - 1);              // tail (tc even -> buf 0)
        __syncthreads();
        for (int jj = i; jj < tc * OUTW; jj += NT)
            vout[(size_t)t0 * OUTW + jj] = vbuf[jj];
        // chunk-top barrier (after carry/LOADW8) gates vbuf/h1h reuse
    }
}

extern "C" void kernel_launch(void* const* d_in, const int* in_sizes, int n_in,
                              void* d_out, int out_size, void* d_ws, size_t ws_size,
                              hipStream_t stream) {
    const float* x    = (const float*)d_in[0];
    const float* Wih0 = (const float*)d_in[1];
    const float* Whh0 = (const float*)d_in[2];
    const float* bih0 = (const float*)d_in[3];
    const float* bhh0 = (const float*)d_in[4];
    const float* Wih1 = (const float*)d_in[5];
    const float* Whh1 = (const float*)d_in[6];
    const float* bih1 = (const float*)d_in[7];
    const float* bhh1 = (const float*)d_in[8];
    const float* Wlin = (const float*)d_in[9];
    const float* blin = (const float*)d_in[10];
    float* out = (float*)d_out;

    lstm2_fused<<<dim3(BB), dim3(NT), 0, stream>>>(
        x, Wih0, Whh0, bih0, bhh0, Wih1, Whh1, bih1, bhh1, Wlin, blin, out);
}

// Round 20
// 2951.290 us; speedup vs baseline: 1.4627x; 1.3603x over previous
//
#include <hip/hip_runtime.h>

#define BB 256
#define TT 2048
#define HH 128
#define HP 136     // padded h1-row stride (f16): breaks phase-B bank conflicts
#define G4 512
#define INW 4
#define OUTW 4
#define TC 56      // time-chunk (2048 = 36*56 + 32, both even)
#define NT 512

typedef _Float16 f16x8 __attribute__((ext_vector_type(8)));
typedef float    f32x4 __attribute__((ext_vector_type(4)));

#define MFMA(A,B,C) __builtin_amdgcn_mfma_f32_16x16x32_f16((A),(B),(C),0,0,0)

__device__ __forceinline__ float sigm(float x)  { return __fdividef(1.f, 1.f + __expf(-x)); }
__device__ __forceinline__ float tanh_(float x) { return __fdividef(2.f, 1.f + __expf(-2.f*x)) - 1.f; }

// R20 = exact revert to R17 (measured optimum, 2956us). R18 (producer/consumer)
// and R19 (4 waves x 8 tiles) both regressed; R15/R16 throughput cuts were
// neutral. The 8-wave NT=512 geometry with 2 waves/SIMD co-scheduling is the
// best measured point. Remaining cost = serial dependency chain per step
// (ds_read h -> 4-deep MFMA -> select -> ~20 trans ops -> write -> barrier)
// x 4096 steps — a recurrence-latency floor, not a pipe-throughput one.
// Layout (verified R11-R17): A-frag W-tile wrow_j = ((r&3)<<7)|(w<<4)|(j<<2)|(r>>2);
// B-frag h broadcast (wave-uniform); lane (r,kq) owns unit w*16+(r&3)*4+kq.

#define LDF(dst, wrj, kk) do {                                                 \
    const float* p_ = Mp_ + (size_t)(wrj) * HH + (kk)*32 + (kq << 3);          \
    const float4 lo_ = *(const float4*)p_;                                     \
    const float4 hi_ = *(const float4*)(p_ + 4);                               \
    dst = (f16x8){(_Float16)lo_.x,(_Float16)lo_.y,(_Float16)lo_.z,             \
                  (_Float16)lo_.w,(_Float16)hi_.x,(_Float16)hi_.y,             \
                  (_Float16)hi_.z,(_Float16)hi_.w}; } while (0)

#define LOADW(M) do { const float* Mp_ = (M);                                  \
    LDF(w00, wr0,      0); LDF(w01, wr0,      1); LDF(w02, wr0,      2); LDF(w03, wr0,      3); \
    LDF(w10, wr0 + 4,  0); LDF(w11, wr0 + 4,  1); LDF(w12, wr0 + 4,  2); LDF(w13, wr0 + 4,  3); \
    LDF(w20, wr0 + 8,  0); LDF(w21, wr0 + 8,  1); LDF(w22, wr0 + 8,  2); LDF(w23, wr0 + 8,  3); \
    LDF(w30, wr0 + 12, 0); LDF(w31, wr0 + 12, 1); LDF(w32, wr0 + 12, 2); LDF(w33, wr0 + 12, 3); \
} while (0)

#define RSTEP(HB) do {                                                         \
    f16x8 hv_;                                                                 \
    hv_ = *(const f16x8*)((HB) + (kq << 3));                                   \
    a0 = MFMA(w00, hv_, a0); a1 = MFMA(w10, hv_, a1);                          \
    a2 = MFMA(w20, hv_, a2); a3 = MFMA(w30, hv_, a3);                          \
    hv_ = *(const f16x8*)((HB) + 32 + (kq << 3));                              \
    a0 = MFMA(w01, hv_, a0); a1 = MFMA(w11, hv_, a1);                          \
    a2 = MFMA(w21, hv_, a2); a3 = MFMA(w31, hv_, a3);                          \
    hv_ = *(const f16x8*)((HB) + 64 + (kq << 3));                              \
    a0 = MFMA(w02, hv_, a0); a1 = MFMA(w12, hv_, a1);                          \
    a2 = MFMA(w22, hv_, a2); a3 = MFMA(w32, hv_, a3);                          \
    hv_ = *(const f16x8*)((HB) + 96 + (kq << 3));                              \
    a0 = MFMA(w03, hv_, a0); a1 = MFMA(w13, hv_, a1);                          \
    a2 = MFMA(w23, hv_, a2); a3 = MFMA(w33, hv_, a3); } while (0)

// select my tile (j = r&3) from the 4 acc vectors, add xg, LSTM update
#define UPDSEL(CJ, HN, XG) do {                                                \
    f32x4 av_;                                                                 \
    _Pragma("unroll")                                                          \
    for (int e_ = 0; e_ < 4; ++e_) {                                           \
        const float t01_ = j1 ? a1[e_] : a0[e_];                               \
        const float t23_ = j1 ? a3[e_] : a2[e_];                               \
        av_[e_] = (j2 ? t23_ : t01_) + (XG)[e_];                               \
    }                                                                          \
    const float i_ = sigm(av_[0]);                                             \
    const float f_ = sigm(av_[1]);                                             \
    const float g_ = tanh_(av_[2]);                                            \
    const float o_ = sigm(av_[3]);                                             \
    CJ = f_ * CJ + i_ * g_;                                                    \
    HN = o_ * tanh_(CJ); } while (0)

// projection of the h2 snapshot at LDS offset OFS into vbuf slot VT (waves 0-3)
#define PROJ(OFS, VT) do {                                                     \
    if (i < 256) {                                                             \
        float p2 = (float)h2h[(OFS) + pl] * wlA                                \
                 + (float)h2h[(OFS) + 64 + pl] * wlB;                          \
        p2 += __shfl_xor(p2, 32);                                              \
        p2 += __shfl_xor(p2, 16);                                              \
        p2 += __shfl_xor(p2, 8);                                               \
        p2 += __shfl_xor(p2, 4);                                               \
        p2 += __shfl_xor(p2, 2);                                               \
        p2 += __shfl_xor(p2, 1);                                               \
        if (pl == 0) vbuf[(VT) * OUTW + po] = p2 + bl;                         \
    } } while (0)

extern "C" __global__ void
__attribute__((amdgpu_flat_work_group_size(NT, NT)))
lstm2_fused(const float* __restrict__ x,
            const float* __restrict__ Wih0, const float* __restrict__ Whh0,
            const float* __restrict__ bih0, const float* __restrict__ bhh0,
            const float* __restrict__ Wih1, const float* __restrict__ Whh1,
            const float* __restrict__ bih1, const float* __restrict__ bhh1,
            const float* __restrict__ Wlin, const float* __restrict__ blin,
            float* __restrict__ out)
{
    // static LDS: 17,680 + 114,688 + 512 + 896 = 133,776 B
    __shared__ __align__(16) _Float16 h1h[(TC + 9) * HP]; // h1 ring (padded)
    __shared__ __align__(16) float    buf[TC * G4];       // xg0, then xg1
    __shared__ __align__(16) _Float16 h2h[2 * HH];        // h2 dbuf, parity t&1
    __shared__ __align__(16) float    vbuf[TC * OUTW];    // v staging (no vmcnt in-loop)

    const int i    = threadIdx.x;
    const int w    = i >> 6;            // wave 0..7 -> tiles 4w..4w+3
    const int lane = i & 63;
    const int r    = lane & 15;
    const int kq   = lane >> 4;
    const int b    = blockIdx.x;

    const int wr0 = ((r & 3) << 7) | (r >> 2) | (w << 4);
    const bool j1 = (r & 1), j2 = (r & 2);
    const int  myu = (w << 4) | ((r & 3) << 2) | kq;
    const bool own = (r < 4);

    // ---- per-thread kernel-lifetime constants
    const int  rg_row = ((i & 3) << 7) | (i >> 2);        // W-row of gate-col i
    const float4 wv   = *(const float4*)(Wih0 + (size_t)rg_row * INW);
    const float  b0r  = bih0[rg_row] + bhh0[rg_row];
    const float  bb0  = bih1[wr0]      + bhh1[wr0];
    const float  bb1  = bih1[wr0 + 4]  + bhh1[wr0 + 4];
    const float  bb2  = bih1[wr0 + 8]  + bhh1[wr0 + 8];
    const float  bb3  = bih1[wr0 + 12] + bhh1[wr0 + 12];
    // projection constants (threads 0..255: output o = wave, lane-part l)
    const int   po = i >> 6;
    const int   pl = i & 63;
    const float wlA = (i < 256) ? Wlin[po * HH + pl]      : 0.f;
    const float wlB = (i < 256) ? Wlin[po * HH + 64 + pl] : 0.f;
    const float bl  = (i < 256) ? blin[po] : 0.f;

    if (i < HH) { h1h[i] = (_Float16)0.f; h2h[i] = (_Float16)0.f; }

    float c1 = 0.f, c2 = 0.f;
    f16x8 w00, w01, w02, w03, w10, w11, w12, w13,
          w20, w21, w22, w23, w30, w31, w32, w33;

    const float* xb   = x   + (size_t)b * TT * INW;
    float*       vout = out + (size_t)b * TT * OUTW;
    float*       zout = out + (size_t)BB * TT * OUTW + (size_t)b * HH;

    for (int t0 = 0; t0 < TT; t0 += TC) {
        const int tc = (TT - t0 < TC) ? (TT - t0) : TC;

        if (t0 > 0 && i < HH) h1h[i] = h1h[TC * HP + i];   // carry h1 ring
        // xg0 bulk: buf[t][i] = b0r + Wih0[row].x_t  (x via L1 broadcast)
        for (int t = 0; t < tc; ++t) {
            const float4 xv = *(const float4*)(xb + (size_t)(t0 + t) * INW);
            buf[t * G4 + i] = b0r + wv.x*xv.x + wv.y*xv.y + wv.z*xv.z + wv.w*xv.w;
        }
        LOADW(Whh0);
        __syncthreads();

        // ================= Phase A: layer-0 recurrence =================
        for (int t = 0; t < tc; ++t) {
            f32x4 a0 = {0.f,0.f,0.f,0.f}, a1 = {0.f,0.f,0.f,0.f},
                  a2 = {0.f,0.f,0.f,0.f}, a3 = {0.f,0.f,0.f,0.f};
            RSTEP(h1h + t * HP);
            const f32x4 xg = *(const f32x4*)(buf + t * G4 + (myu << 2));
            float hn;
            UPDSEL(c1, hn, xg);
            if (own) h1h[(t + 1) * HP + myu] = (_Float16)hn;
            __syncthreads();
        }

        // ===== Phase B: xg1 = Wih1 @ h1 + b1 (bulk, A = h1 time-rows) =====
        LOADW(Wih1);
        const int ntb = (tc + 15) >> 4;
        for (int tb = 0; tb < ntb; ++tb) {
            f32x4 a0 = {0.f,0.f,0.f,0.f}, a1 = {0.f,0.f,0.f,0.f},
                  a2 = {0.f,0.f,0.f,0.f}, a3 = {0.f,0.f,0.f,0.f};
            const _Float16* ha = h1h + (tb * 16 + r + 1) * HP;
            f16x8 tv;
            tv = *(const f16x8*)(ha + (kq << 3));
            a0 = MFMA(tv, w00, a0); a1 = MFMA(tv, w10, a1);
            a2 = MFMA(tv, w20, a2); a3 = MFMA(tv, w30, a3);
            tv = *(const f16x8*)(ha + 32 + (kq << 3));
            a0 = MFMA(tv, w01, a0); a1 = MFMA(tv, w11, a1);
            a2 = MFMA(tv, w21, a2); a3 = MFMA(tv, w31, a3);
            tv = *(const f16x8*)(ha + 64 + (kq << 3));
            a0 = MFMA(tv, w02, a0); a1 = MFMA(tv, w12, a1);
            a2 = MFMA(tv, w22, a2); a3 = MFMA(tv, w32, a3);
            tv = *(const f16x8*)(ha + 96 + (kq << 3));
            a0 = MFMA(tv, w03, a0); a1 = MFMA(tv, w13, a1);
            a2 = MFMA(tv, w23, a2); a3 = MFMA(tv, w33, a3);
            #pragma unroll
            for (int e = 0; e < 4; ++e) {       // C row = local time
                const int tl = tb * 16 + (kq << 2) + e;
                if (tl < tc) {
                    float* bq = buf + tl * G4 + (w << 6) + r;
                    bq[0]  = a0[e] + bb0;
                    bq[16] = a1[e] + bb1;
                    bq[32] = a2[e] + bb2;
                    bq[48] = a3[e] + bb3;
                }
            }
        }
        __syncthreads();

        // ====== Phase C: layer-1 recurrence; projection pipelined by 1 ==
        LOADW(Whh1);
        for (int t = 0; t < tc; ++t) {
            const int rb = (t & 1) * HH, wbuf2 = rb ^ HH;
            f32x4 a0 = {0.f,0.f,0.f,0.f}, a1 = {0.f,0.f,0.f,0.f},
                  a2 = {0.f,0.f,0.f,0.f}, a3 = {0.f,0.f,0.f,0.f};
            RSTEP(h2h + rb);
            // project h2[t-1] (same stable buffer) under the MFMA shadow
            if (t > 0) PROJ(rb, t - 1);
            const f32x4 xg = *(const f32x4*)(buf + t * G4 + (myu << 2));
            float hn;
            UPDSEL(c2, hn, xg);
            if (own) {
                h2h[wbuf2 + myu] = (_Float16)hn;
                if (t0 + t == TT - 1) zout[myu] = hn;   // once per kernel
            }
            __syncthreads();
        }
        // tail: project h2[tc-1] (sits at offset rb(tc) = (tc&1)*HH)
        PROJ((tc & 1) * HH, tc - 1);
        __syncthreads();
        // bulk v store: one vmcnt drain per chunk instead of per step
        for (int j = i; j < tc * OUTW; j += NT)
            vout[(size_t)t0 * OUTW + j] = vbuf[j];
        // chunk-top barrier (after carry/xg0) gates next chunk vs these reads
    }
}

extern "C" void kernel_launch(void* const* d_in, const int* in_sizes, int n_in,
                              void* d_out, int out_size, void* d_ws, size_t ws_size,
                              hipStream_t stream) {
    const float* x    = (const float*)d_in[0];
    const float* Wih0 = (const float*)d_in[1];
    const float* Whh0 = (const float*)d_in[2];
    const float* bih0 = (const float*)d_in[3];
    const float* bhh0 = (const float*)d_in[4];
    const float* Wih1 = (const float*)d_in[5];
    const float* Whh1 = (const float*)d_in[6];
    const float* bih1 = (const float*)d_in[7];
    const float* bhh1 = (const float*)d_in[8];
    const float* Wlin = (const float*)d_in[9];
    const float* blin = (const float*)d_in[10];
    float* out = (float*)d_out;

    lstm2_fused<<<dim3(BB), dim3(NT), 0, stream>>>(
        x, Wih0, Whh0, bih0, bhh0, Wih1, Whh1, bih1, bhh1, Wlin, blin, out);
}